// Round 1
// baseline (117.767 us; speedup 1.0000x reference)
//
#include <hip/hip_runtime.h>
#include <hip/hip_bf16.h>

// Per-edge dot product: out[e] = dot(h[src[e]], h[dst[e]]), D=128 fp32.
// 32 lanes per edge: lane i loads float4 #i of each row (512 B coalesced),
// 4 FMAs, then shfl_xor reduction over the 32-lane group.

#define D 128
#define LANES_PER_EDGE 32

__global__ __launch_bounds__(256) void edge_dot_kernel(
    const float* __restrict__ h,
    const int* __restrict__ src,
    const int* __restrict__ dst,
    float* __restrict__ out,
    int E)
{
    int tid  = blockIdx.x * blockDim.x + threadIdx.x;
    int edge = tid >> 5;        // 32 lanes per edge
    int lane = tid & 31;
    if (edge >= E) return;

    int s = src[edge];
    int d = dst[edge];

    const float4* hu = reinterpret_cast<const float4*>(h + (size_t)s * D);
    const float4* hv = reinterpret_cast<const float4*>(h + (size_t)d * D);

    float4 a = hu[lane];
    float4 b = hv[lane];
    float sum = a.x * b.x + a.y * b.y + a.z * b.z + a.w * b.w;

    // Reduce across the 32-lane group (xor masks < 32 stay within the group).
    #pragma unroll
    for (int off = 16; off > 0; off >>= 1)
        sum += __shfl_xor(sum, off);

    if (lane == 0)
        out[edge] = sum;
}

extern "C" void kernel_launch(void* const* d_in, const int* in_sizes, int n_in,
                              void* d_out, int out_size, void* d_ws, size_t ws_size,
                              hipStream_t stream)
{
    const float* h   = (const float*)d_in[0];
    const int*   src = (const int*)d_in[1];
    const int*   dst = (const int*)d_in[2];
    float*       out = (float*)d_out;

    int E = in_sizes[1];  // 640000 edges

    int threads = 256;
    long long total = (long long)E * LANES_PER_EDGE;
    int blocks = (int)((total + threads - 1) / threads);

    edge_dot_kernel<<<blocks, threads, 0, stream>>>(h, src, dst, out, E);
}

// Round 2
// 93.178 us; speedup vs baseline: 1.2639x; 1.2639x over previous
//
#include <hip/hip_runtime.h>
#include <hip/hip_bf16.h>

// Per-edge dot product: out[e] = dot(h[src[e]], h[dst[e]]), D=128 fp32.
// 8 lanes per edge; lane l loads float4s {l, l+8, l+16, l+24} of each row
// (interleaved so each load instruction covers a contiguous 128 B block per
// edge -> coalesced, and offsets are compile-time immediates). 8 loads in
// flight per lane, then 3-step shfl_xor reduction over the 8-lane group.

#define D 128

__global__ __launch_bounds__(256) void edge_dot_kernel(
    const float* __restrict__ h,
    const int* __restrict__ src,
    const int* __restrict__ dst,
    float* __restrict__ out,
    int E)
{
    int tid  = blockIdx.x * blockDim.x + threadIdx.x;
    int edge = tid >> 3;        // 8 lanes per edge
    int lane = tid & 7;
    if (edge >= E) return;

    int s = src[edge];
    int d = dst[edge];

    const float4* hu = reinterpret_cast<const float4*>(h + (size_t)s * D) + lane;
    const float4* hv = reinterpret_cast<const float4*>(h + (size_t)d * D) + lane;

    // 8 independent 16B loads in flight (offsets 0/128/256/384 B as immediates).
    float4 a0 = hu[0];
    float4 a1 = hu[8];
    float4 a2 = hu[16];
    float4 a3 = hu[24];
    float4 b0 = hv[0];
    float4 b1 = hv[8];
    float4 b2 = hv[16];
    float4 b3 = hv[24];

    float sum = a0.x * b0.x + a0.y * b0.y + a0.z * b0.z + a0.w * b0.w;
    sum += a1.x * b1.x + a1.y * b1.y + a1.z * b1.z + a1.w * b1.w;
    sum += a2.x * b2.x + a2.y * b2.y + a2.z * b2.z + a2.w * b2.w;
    sum += a3.x * b3.x + a3.y * b3.y + a3.z * b3.z + a3.w * b3.w;

    // Reduce across the 8-lane group.
    sum += __shfl_xor(sum, 4);
    sum += __shfl_xor(sum, 2);
    sum += __shfl_xor(sum, 1);

    if (lane == 0)
        out[edge] = sum;
}

extern "C" void kernel_launch(void* const* d_in, const int* in_sizes, int n_in,
                              void* d_out, int out_size, void* d_ws, size_t ws_size,
                              hipStream_t stream)
{
    const float* h   = (const float*)d_in[0];
    const int*   src = (const int*)d_in[1];
    const int*   dst = (const int*)d_in[2];
    float*       out = (float*)d_out;

    int E = in_sizes[1];  // 640000 edges

    int threads = 256;
    long long total = (long long)E * 8;
    int blocks = (int)((total + threads - 1) / threads);

    edge_dot_kernel<<<blocks, threads, 0, stream>>>(h, src, dst, out, E);
}

// Round 3
// 80.112 us; speedup vs baseline: 1.4700x; 1.1631x over previous
//
#include <hip/hip_runtime.h>
#include <hip/hip_bf16.h>

// out[e] = dot(h[src[e]], h[dst[e]]), E=640k, D=128 fp32.
// Strategy: per-launch convert h (5.12 MB fp32) -> bf16 (2.56 MB) in d_ws so
// the random-gather working set fits a single XCD's 4 MiB L2 (fp32 h thrashed
// it: 97 MB L3 fetch in round 1). Gather traffic also halves (655->327 MB).
// bf16->fp32 expansion is a shift/mask, accumulation stays fp32.
// 8 lanes/edge, 2x uint4 loads per lane per row (4 gather instrs per wave).

#define D 128

__device__ __forceinline__ unsigned short f32_to_bf16_rne(float f) {
    unsigned int u = __float_as_uint(f);
    unsigned int lsb = (u >> 16) & 1u;
    u += 0x7fffu + lsb;          // round-to-nearest-even
    return (unsigned short)(u >> 16);
}

__global__ __launch_bounds__(256) void convert_bf16_kernel(
    const float* __restrict__ h, unsigned short* __restrict__ hb, int n4)
{
    int i = blockIdx.x * blockDim.x + threadIdx.x;
    if (i >= n4) return;
    float4 v = reinterpret_cast<const float4*>(h)[i];
    ushort4 o;
    o.x = f32_to_bf16_rne(v.x);
    o.y = f32_to_bf16_rne(v.y);
    o.z = f32_to_bf16_rne(v.z);
    o.w = f32_to_bf16_rne(v.w);
    reinterpret_cast<ushort4*>(hb)[i] = o;
}

// dot of 2 bf16 pairs packed in uints (hi/lo 16 bits), fp32 accumulate
__device__ __forceinline__ float bfdot2(unsigned int a, unsigned int b) {
    float alo = __uint_as_float(a << 16);
    float ahi = __uint_as_float(a & 0xffff0000u);
    float blo = __uint_as_float(b << 16);
    float bhi = __uint_as_float(b & 0xffff0000u);
    return alo * blo + ahi * bhi;
}

__device__ __forceinline__ float bfdot8(uint4 a, uint4 b) {
    return bfdot2(a.x, b.x) + bfdot2(a.y, b.y) +
           bfdot2(a.z, b.z) + bfdot2(a.w, b.w);
}

__global__ __launch_bounds__(256) void edge_dot_bf16_kernel(
    const unsigned short* __restrict__ hb,
    const int* __restrict__ src,
    const int* __restrict__ dst,
    float* __restrict__ out,
    int E)
{
    int tid  = blockIdx.x * blockDim.x + threadIdx.x;
    int edge = tid >> 3;   // 8 lanes per edge
    int lane = tid & 7;
    if (edge >= E) return;

    int s = src[edge];
    int d = dst[edge];

    // row = 128 bf16 = 256 B = 16 uint4; lane covers uint4 {lane, lane+8}
    const uint4* pu = reinterpret_cast<const uint4*>(hb + (size_t)s * D);
    const uint4* pv = reinterpret_cast<const uint4*>(hb + (size_t)d * D);

    uint4 a0 = pu[lane];
    uint4 a1 = pu[lane + 8];
    uint4 b0 = pv[lane];
    uint4 b1 = pv[lane + 8];

    float sum = bfdot8(a0, b0) + bfdot8(a1, b1);

    sum += __shfl_xor(sum, 4);
    sum += __shfl_xor(sum, 2);
    sum += __shfl_xor(sum, 1);

    if (lane == 0)
        out[edge] = sum;
}

// Fallback (fp32 direct gather) if ws is too small for the bf16 table.
__global__ __launch_bounds__(256) void edge_dot_f32_kernel(
    const float* __restrict__ h,
    const int* __restrict__ src,
    const int* __restrict__ dst,
    float* __restrict__ out,
    int E)
{
    int tid  = blockIdx.x * blockDim.x + threadIdx.x;
    int edge = tid >> 3;
    int lane = tid & 7;
    if (edge >= E) return;

    int s = src[edge];
    int d = dst[edge];

    const float4* hu = reinterpret_cast<const float4*>(h + (size_t)s * D) + lane;
    const float4* hv = reinterpret_cast<const float4*>(h + (size_t)d * D) + lane;

    float4 a0 = hu[0], a1 = hu[8], a2 = hu[16], a3 = hu[24];
    float4 b0 = hv[0], b1 = hv[8], b2 = hv[16], b3 = hv[24];

    float sum = a0.x * b0.x + a0.y * b0.y + a0.z * b0.z + a0.w * b0.w;
    sum += a1.x * b1.x + a1.y * b1.y + a1.z * b1.z + a1.w * b1.w;
    sum += a2.x * b2.x + a2.y * b2.y + a2.z * b2.z + a2.w * b2.w;
    sum += a3.x * b3.x + a3.y * b3.y + a3.z * b3.z + a3.w * b3.w;

    sum += __shfl_xor(sum, 4);
    sum += __shfl_xor(sum, 2);
    sum += __shfl_xor(sum, 1);

    if (lane == 0)
        out[edge] = sum;
}

extern "C" void kernel_launch(void* const* d_in, const int* in_sizes, int n_in,
                              void* d_out, int out_size, void* d_ws, size_t ws_size,
                              hipStream_t stream)
{
    const float* h   = (const float*)d_in[0];
    const int*   src = (const int*)d_in[1];
    const int*   dst = (const int*)d_in[2];
    float*       out = (float*)d_out;

    int E = in_sizes[1];            // 640000 edges
    int hN = in_sizes[0];           // N_NODES * 128 floats
    size_t need = (size_t)hN * sizeof(unsigned short);

    int threads = 256;
    long long total = (long long)E * 8;
    int blocks = (int)((total + threads - 1) / threads);

    if (ws_size >= need) {
        unsigned short* hb = (unsigned short*)d_ws;
        int n4 = hN / 4;
        convert_bf16_kernel<<<(n4 + threads - 1) / threads, threads, 0, stream>>>(h, hb, n4);
        edge_dot_bf16_kernel<<<blocks, threads, 0, stream>>>(hb, src, dst, out, E);
    } else {
        edge_dot_f32_kernel<<<blocks, threads, 0, stream>>>(h, src, dst, out, E);
    }
}

// Round 4
// 79.145 us; speedup vs baseline: 1.4880x; 1.0122x over previous
//
#include <hip/hip_runtime.h>
#include <hip/hip_bf16.h>

// out[e] = dot(h[src[e]], h[dst[e]]), E=640k, D=128 fp32.
// h is converted once per launch to bf16 in d_ws (2.56 MB -> fits each XCD's
// 4 MiB L2; fp32 version thrashed it at 97 MB L3 fetch). Edge kernel: 8 lanes
// per edge, 2 edges per lane-group -> 8 independent uint4 gathers in flight
// per lane, one waitcnt, 6 shuffles, one float2 store per 2 edges.

#define D 128

__device__ __forceinline__ unsigned short f32_to_bf16_rne(float f) {
    unsigned int u = __float_as_uint(f);
    unsigned int lsb = (u >> 16) & 1u;
    u += 0x7fffu + lsb;          // round-to-nearest-even
    return (unsigned short)(u >> 16);
}

__global__ __launch_bounds__(256) void convert_bf16_kernel(
    const float* __restrict__ h, unsigned short* __restrict__ hb, int n4)
{
    int i = blockIdx.x * blockDim.x + threadIdx.x;
    if (i >= n4) return;
    float4 v = reinterpret_cast<const float4*>(h)[i];
    ushort4 o;
    o.x = f32_to_bf16_rne(v.x);
    o.y = f32_to_bf16_rne(v.y);
    o.z = f32_to_bf16_rne(v.z);
    o.w = f32_to_bf16_rne(v.w);
    reinterpret_cast<ushort4*>(hb)[i] = o;
}

// dot of 2 bf16 pairs packed in a uint (lo/hi 16 bits), fp32 accumulate
__device__ __forceinline__ float bfdot2(unsigned int a, unsigned int b) {
    float alo = __uint_as_float(a << 16);
    float ahi = __uint_as_float(a & 0xffff0000u);
    float blo = __uint_as_float(b << 16);
    float bhi = __uint_as_float(b & 0xffff0000u);
    return alo * blo + ahi * bhi;
}

__device__ __forceinline__ float bfdot8(uint4 a, uint4 b) {
    return bfdot2(a.x, b.x) + bfdot2(a.y, b.y) +
           bfdot2(a.z, b.z) + bfdot2(a.w, b.w);
}

__global__ __launch_bounds__(256) void edge_dot_bf16x2_kernel(
    const unsigned short* __restrict__ hb,
    const int* __restrict__ src,
    const int* __restrict__ dst,
    float* __restrict__ out,
    int E)   // E assumed even (640000)
{
    int tid   = blockIdx.x * blockDim.x + threadIdx.x;
    int group = tid >> 3;        // 8 lanes per group, 2 edges per group
    int lane  = tid & 7;
    int e0 = group * 2;
    if (e0 >= E) return;
    int e1 = e0 + 1;

    int s0 = src[e0];
    int d0 = dst[e0];
    int s1 = src[e1];
    int d1 = dst[e1];

    // row = 128 bf16 = 256 B = 16 uint4; lane covers uint4 {lane, lane+8}
    const uint4* pu0 = reinterpret_cast<const uint4*>(hb + (size_t)s0 * D);
    const uint4* pv0 = reinterpret_cast<const uint4*>(hb + (size_t)d0 * D);
    const uint4* pu1 = reinterpret_cast<const uint4*>(hb + (size_t)s1 * D);
    const uint4* pv1 = reinterpret_cast<const uint4*>(hb + (size_t)d1 * D);

    // 8 independent gather loads in flight per lane
    uint4 a00 = pu0[lane];
    uint4 a01 = pu0[lane + 8];
    uint4 b00 = pv0[lane];
    uint4 b01 = pv0[lane + 8];
    uint4 a10 = pu1[lane];
    uint4 a11 = pu1[lane + 8];
    uint4 b10 = pv1[lane];
    uint4 b11 = pv1[lane + 8];

    float sum0 = bfdot8(a00, b00) + bfdot8(a01, b01);
    float sum1 = bfdot8(a10, b10) + bfdot8(a11, b11);

    sum0 += __shfl_xor(sum0, 4);
    sum1 += __shfl_xor(sum1, 4);
    sum0 += __shfl_xor(sum0, 2);
    sum1 += __shfl_xor(sum1, 2);
    sum0 += __shfl_xor(sum0, 1);
    sum1 += __shfl_xor(sum1, 1);

    if (lane == 0) {
        float2 o = make_float2(sum0, sum1);
        reinterpret_cast<float2*>(out)[group] = o;
    }
}

// Fallback (fp32 direct gather) if ws is too small for the bf16 table.
__global__ __launch_bounds__(256) void edge_dot_f32_kernel(
    const float* __restrict__ h,
    const int* __restrict__ src,
    const int* __restrict__ dst,
    float* __restrict__ out,
    int E)
{
    int tid  = blockIdx.x * blockDim.x + threadIdx.x;
    int edge = tid >> 3;
    int lane = tid & 7;
    if (edge >= E) return;

    int s = src[edge];
    int d = dst[edge];

    const float4* hu = reinterpret_cast<const float4*>(h + (size_t)s * D) + lane;
    const float4* hv = reinterpret_cast<const float4*>(h + (size_t)d * D) + lane;

    float4 a0 = hu[0], a1 = hu[8], a2 = hu[16], a3 = hu[24];
    float4 b0 = hv[0], b1 = hv[8], b2 = hv[16], b3 = hv[24];

    float sum = a0.x * b0.x + a0.y * b0.y + a0.z * b0.z + a0.w * b0.w;
    sum += a1.x * b1.x + a1.y * b1.y + a1.z * b1.z + a1.w * b1.w;
    sum += a2.x * b2.x + a2.y * b2.y + a2.z * b2.z + a2.w * b2.w;
    sum += a3.x * b3.x + a3.y * b3.y + a3.z * b3.z + a3.w * b3.w;

    sum += __shfl_xor(sum, 4);
    sum += __shfl_xor(sum, 2);
    sum += __shfl_xor(sum, 1);

    if (lane == 0)
        out[edge] = sum;
}

extern "C" void kernel_launch(void* const* d_in, const int* in_sizes, int n_in,
                              void* d_out, int out_size, void* d_ws, size_t ws_size,
                              hipStream_t stream)
{
    const float* h   = (const float*)d_in[0];
    const int*   src = (const int*)d_in[1];
    const int*   dst = (const int*)d_in[2];
    float*       out = (float*)d_out;

    int E = in_sizes[1];            // 640000 edges
    int hN = in_sizes[0];           // N_NODES * 128 floats
    size_t need = (size_t)hN * sizeof(unsigned short);

    int threads = 256;

    if (ws_size >= need && (E & 1) == 0) {
        unsigned short* hb = (unsigned short*)d_ws;
        int n4 = hN / 4;
        convert_bf16_kernel<<<(n4 + threads - 1) / threads, threads, 0, stream>>>(h, hb, n4);
        long long total = (long long)(E / 2) * 8;   // 8 lanes per 2 edges
        int blocks = (int)((total + threads - 1) / threads);
        edge_dot_bf16x2_kernel<<<blocks, threads, 0, stream>>>(hb, src, dst, out, E);
    } else {
        long long total = (long long)E * 8;
        int blocks = (int)((total + threads - 1) / threads);
        edge_dot_f32_kernel<<<blocks, threads, 0, stream>>>(h, src, dst, out, E);
    }
}